// Round 1
// baseline (826.991 us; speedup 1.0000x reference)
//
#include <hip/hip_runtime.h>
#include <hip/hip_bf16.h>
#include <string.h>

typedef __attribute__((ext_vector_type(8))) short short8;
typedef __attribute__((ext_vector_type(4))) float f32x4;

#define D_DIM 256
#define NC_DIM 32
#define KV_PAD 260   // 256+4: scores-phase column reads land 4-way max (1.58x), m-phase stride-1

__device__ __forceinline__ ushort f2bf(float x) {
    union { float f; unsigned u; } v; v.f = x;
    unsigned r = (v.u + 0x7fffu + ((v.u >> 16) & 1u)) >> 16;  // RNE
    return (ushort)r;
}
__device__ __forceinline__ float bf2f(ushort u) {
    union { unsigned u32; float f; } v; v.u32 = ((unsigned)u) << 16;
    return v.f;
}

// Bc2t[(h*256+d)][i] = sum_j Wq[h*64+j, i] * Wkv[h*64+j, d]   (bf16, [1024 x 256], K-major)
__global__ __launch_bounds__(256)
void k_combine_B(const float* __restrict__ Wq, const float* __restrict__ Wkv,
                 ushort* __restrict__ Bc2t) {
    int bid = blockIdx.x;
    int h = bid >> 8, d = bid & 255;
    int i = threadIdx.x;
    __shared__ float wk_s[64];
    if (i < 64) wk_s[i] = Wkv[(size_t)(h * 64 + i) * D_DIM + d];
    __syncthreads();
    float s = 0.f;
#pragma unroll 8
    for (int j = 0; j < 64; j++)
        s = fmaf(Wq[(size_t)(h * 64 + j) * D_DIM + i], wk_s[j], s);
    Bc2t[(size_t)(h * 256 + d) * D_DIM + i] = f2bf(s);
}

// Cc2t[i][h*256+d] = sum_dk Wkv[256 + h*64+dk, d] * Wout[i, h*64+dk]  (bf16, [256 x 1024], K-major)
__global__ __launch_bounds__(256)
void k_combine_C(const float* __restrict__ Wkv, const float* __restrict__ Wout,
                 ushort* __restrict__ Cc2t) {
    int bid = blockIdx.x;
    int h = bid >> 8, i = bid & 255;
    int d = threadIdx.x;
    __shared__ float wo_s[64];
    if (d < 64) wo_s[d] = Wout[(size_t)i * D_DIM + h * 64 + d];
    __syncthreads();
    const float* Wv = Wkv + 256 * D_DIM;
    float s = 0.f;
#pragma unroll 8
    for (int dk = 0; dk < 64; dk++)
        s = fmaf(Wv[(size_t)(h * 64 + dk) * D_DIM + d], wo_s[dk], s);
    Cc2t[(size_t)i * 1024 + h * 256 + d] = f2bf(s);
}

// C[M,N] = A[M,K] @ Bt[N,K]^T  via 16x16x32 bf16 MFMA. BM=BN=64, BK=32, 256 thr (4 waves).
// A_F32: A is fp32 (converted to bf16 at LDS stage). EPI_RES: C fp32 = acc + resid + bias,
// else C bf16.
template <bool A_F32, bool EPI_RES>
__global__ __launch_bounds__(256)
void k_gemm(const void* __restrict__ Ap, const ushort* __restrict__ Bt,
            void* __restrict__ Cp, const float* __restrict__ resid,
            const float* __restrict__ bias, int M, int N, int K) {
    __shared__ ushort As[64][40];  // pad 32->40: frag b128 reads ~2-way (free)
    __shared__ ushort Bs[64][40];
    const int tid = threadIdx.x;
    const int m0 = blockIdx.y * 64, n0 = blockIdx.x * 64;
    const int w = tid >> 6, L = tid & 63;
    const int ar = tid >> 2, ac = (tid & 3) * 8;
    f32x4 acc0 = {0.f, 0.f, 0.f, 0.f}, acc1 = {0.f, 0.f, 0.f, 0.f};
    f32x4 acc2 = {0.f, 0.f, 0.f, 0.f}, acc3 = {0.f, 0.f, 0.f, 0.f};

    for (int k0 = 0; k0 < K; k0 += 32) {
        __syncthreads();
        if (A_F32) {
            const float* A = (const float*)Ap;
            const float* src = A + (size_t)(m0 + ar) * K + k0 + ac;
            float4 v0 = *(const float4*)src;
            float4 v1 = *(const float4*)(src + 4);
            union { ushort us[8]; uint4 v; } pk;
            pk.us[0] = f2bf(v0.x); pk.us[1] = f2bf(v0.y);
            pk.us[2] = f2bf(v0.z); pk.us[3] = f2bf(v0.w);
            pk.us[4] = f2bf(v1.x); pk.us[5] = f2bf(v1.y);
            pk.us[6] = f2bf(v1.z); pk.us[7] = f2bf(v1.w);
            *(uint4*)&As[ar][ac] = pk.v;
        } else {
            const ushort* A = (const ushort*)Ap;
            *(uint4*)&As[ar][ac] = *(const uint4*)(A + (size_t)(m0 + ar) * K + k0 + ac);
        }
        *(uint4*)&Bs[ar][ac] = *(const uint4*)(Bt + (size_t)(n0 + ar) * K + k0 + ac);
        __syncthreads();
        // A-operand: lane holds A[m=L&15][k=(L>>4)*8+j]; B-operand mirror from Bt rows.
        short8 af = *(const short8*)&As[w * 16 + (L & 15)][(L >> 4) * 8];
        short8 b0 = *(const short8*)&Bs[0 + (L & 15)][(L >> 4) * 8];
        short8 b1 = *(const short8*)&Bs[16 + (L & 15)][(L >> 4) * 8];
        short8 b2 = *(const short8*)&Bs[32 + (L & 15)][(L >> 4) * 8];
        short8 b3 = *(const short8*)&Bs[48 + (L & 15)][(L >> 4) * 8];
        acc0 = __builtin_amdgcn_mfma_f32_16x16x32_bf16(af, b0, acc0, 0, 0, 0);
        acc1 = __builtin_amdgcn_mfma_f32_16x16x32_bf16(af, b1, acc1, 0, 0, 0);
        acc2 = __builtin_amdgcn_mfma_f32_16x16x32_bf16(af, b2, acc2, 0, 0, 0);
        acc3 = __builtin_amdgcn_mfma_f32_16x16x32_bf16(af, b3, acc3, 0, 0, 0);
    }
    // C/D layout: col = L&15, row = (L>>4)*4 + reg
    const int row_base = m0 + w * 16 + (L >> 4) * 4;
    const int col_base = n0 + (L & 15);
    f32x4 accs[4] = {acc0, acc1, acc2, acc3};
#pragma unroll
    for (int nt = 0; nt < 4; nt++) {
        int col = col_base + nt * 16;
#pragma unroll
        for (int r = 0; r < 4; r++) {
            int row = row_base + r;
            float v = accs[nt][r];
            if (EPI_RES) {
                ((float*)Cp)[(size_t)row * N + col] =
                    v + resid[(size_t)row * N + col] + bias[col];
            } else {
                ((ushort*)Cp)[(size_t)row * N + col] = f2bf(v);
            }
        }
    }
}

// Per-row fused attention. Reads A2 row (bf16), child chunk + pos_emb gather -> kvin (LDS),
// scores = kvin . A (fp32), softmax over n per head, m = att-weighted kvin sum,
// writes m2 (bf16) IN PLACE over the A2 row (read fully before write, barrier-ordered).
__global__ __launch_bounds__(256)
void k_attn(const float* __restrict__ child, const int* __restrict__ idx,
            const float* __restrict__ pos_emb, ushort* __restrict__ Am) {
    __shared__ int idx_s[NC_DIM];
    __shared__ float A_s[4][KV_PAD];
    __shared__ float kv_s[NC_DIM][KV_PAD];
    __shared__ float part_s[8][NC_DIM][4];
    __shared__ float att_s[NC_DIM][4];
    __shared__ float mpart_s[4][4][D_DIM];
    const int b = blockIdx.x;
    const int t = threadIdx.x;

    if (t < NC_DIM) idx_s[t] = idx[(size_t)b * NC_DIM + t];
    if (t < 128) {
        uint4 raw = *(const uint4*)(Am + (size_t)b * 1024 + t * 8);
        const ushort* u = (const ushort*)&raw;
        int h = t >> 5, c = (t & 31) * 8;
#pragma unroll
        for (int j = 0; j < 8; j++) A_s[h][c + j] = bf2f(u[j]);
    }
    __syncthreads();

    // stage kvin = child + pos_emb[idx]  (fully coalesced float4)
    const float4* ch4 = (const float4*)(child + (size_t)b * NC_DIM * D_DIM);
#pragma unroll
    for (int i = 0; i < 8; i++) {
        int f = t + i * 256;  // float4 index 0..2047
        int n = f >> 6, c4 = f & 63;
        float4 cv = ch4[f];
        float4 pv = ((const float4*)(pos_emb + (size_t)idx_s[n] * D_DIM))[c4];
        float4 r;
        r.x = cv.x + pv.x; r.y = cv.y + pv.y; r.z = cv.z + pv.z; r.w = cv.w + pv.w;
        *(float4*)&kv_s[n][c4 * 4] = r;
    }
    __syncthreads();

    // scores partials: thread (n = t&31, chunk c = t>>5 of 32 d's), all 4 heads per kv read
    {
        int n = t & 31, c = t >> 5;
        float s0 = 0, s1 = 0, s2 = 0, s3 = 0;
#pragma unroll
        for (int j = 0; j < 32; j += 4) {
            float4 kv = *(const float4*)&kv_s[n][c * 32 + j];
            float4 a0 = *(const float4*)&A_s[0][c * 32 + j];
            float4 a1 = *(const float4*)&A_s[1][c * 32 + j];
            float4 a2 = *(const float4*)&A_s[2][c * 32 + j];
            float4 a3 = *(const float4*)&A_s[3][c * 32 + j];
            s0 += kv.x * a0.x + kv.y * a0.y + kv.z * a0.z + kv.w * a0.w;
            s1 += kv.x * a1.x + kv.y * a1.y + kv.z * a1.z + kv.w * a1.w;
            s2 += kv.x * a2.x + kv.y * a2.y + kv.z * a2.z + kv.w * a2.w;
            s3 += kv.x * a3.x + kv.y * a3.y + kv.z * a3.z + kv.w * a3.w;
        }
        part_s[c][n][0] = s0; part_s[c][n][1] = s1;
        part_s[c][n][2] = s2; part_s[c][n][3] = s3;
    }
    __syncthreads();

    // combine + softmax over n (32-lane shfl groups; lanes of one h-group are contiguous)
    if (t < 128) {
        int n = t & 31, h = t >> 5;
        float s = 0;
#pragma unroll
        for (int c = 0; c < 8; c++) s += part_s[c][n][h];
        s *= 0.125f;  // DK^-0.5
        float mx = s;
#pragma unroll
        for (int off = 16; off; off >>= 1) mx = fmaxf(mx, __shfl_xor(mx, off, 32));
        float e = __expf(s - mx);
        float sum = e;
#pragma unroll
        for (int off = 16; off; off >>= 1) sum += __shfl_xor(sum, off, 32);
        att_s[n][h] = e / sum;
    }
    __syncthreads();

    // m partials: thread (d4 = t&63 float4-col, g = t>>6 covers 8 n), all 4 heads per kv read
    {
        int d4 = t & 63, g = t >> 6;
        float4 a0 = {0, 0, 0, 0}, a1 = {0, 0, 0, 0}, a2 = {0, 0, 0, 0}, a3 = {0, 0, 0, 0};
#pragma unroll
        for (int nn = 0; nn < 8; nn++) {
            int n = g * 8 + nn;
            float4 kv = *(const float4*)&kv_s[n][d4 * 4];
            float w0 = att_s[n][0], w1 = att_s[n][1], w2 = att_s[n][2], w3 = att_s[n][3];
            a0.x += w0 * kv.x; a0.y += w0 * kv.y; a0.z += w0 * kv.z; a0.w += w0 * kv.w;
            a1.x += w1 * kv.x; a1.y += w1 * kv.y; a1.z += w1 * kv.z; a1.w += w1 * kv.w;
            a2.x += w2 * kv.x; a2.y += w2 * kv.y; a2.z += w2 * kv.z; a2.w += w2 * kv.w;
            a3.x += w3 * kv.x; a3.y += w3 * kv.y; a3.z += w3 * kv.z; a3.w += w3 * kv.w;
        }
        *(float4*)&mpart_s[g][0][d4 * 4] = a0;
        *(float4*)&mpart_s[g][1][d4 * 4] = a1;
        *(float4*)&mpart_s[g][2][d4 * 4] = a2;
        *(float4*)&mpart_s[g][3][d4 * 4] = a3;
    }
    __syncthreads();

    // reduce groups, write m2 bf16 over the A2 row (layout [h*256+d])
    {
        int h = t >> 6, d4 = t & 63;
        float4 m = {0, 0, 0, 0};
#pragma unroll
        for (int g = 0; g < 4; g++) {
            float4 p = *(const float4*)&mpart_s[g][h][d4 * 4];
            m.x += p.x; m.y += p.y; m.z += p.z; m.w += p.w;
        }
        union { ushort us[4]; uint2 v; } pk;
        pk.us[0] = f2bf(m.x); pk.us[1] = f2bf(m.y);
        pk.us[2] = f2bf(m.z); pk.us[3] = f2bf(m.w);
        *(uint2*)(Am + (size_t)b * 1024 + h * 256 + d4 * 4) = pk.v;
    }
}

// Row-wise LayerNorm: 4 rows/block (one wave each), 64 lanes x float4 = 256 cols
__global__ __launch_bounds__(256)
void k_ln(const float* __restrict__ x, const float* __restrict__ gamma,
          const float* __restrict__ beta, float* __restrict__ out) {
    const int t = threadIdx.x;
    const int w = t >> 6, l = t & 63;
    const size_t row = (size_t)blockIdx.x * 4 + w;
    float4 v = *(const float4*)(x + row * D_DIM + l * 4);
    float s = v.x + v.y + v.z + v.w;
    float q = v.x * v.x + v.y * v.y + v.z * v.z + v.w * v.w;
#pragma unroll
    for (int off = 32; off; off >>= 1) {
        s += __shfl_xor(s, off, 64);
        q += __shfl_xor(q, off, 64);
    }
    float mu = s * (1.f / 256.f);
    float var = q * (1.f / 256.f) - mu * mu;
    float rs = rsqrtf(var + 1e-5f);
    float4 g4 = *(const float4*)(gamma + l * 4);
    float4 b4 = *(const float4*)(beta + l * 4);
    float4 o;
    o.x = (v.x - mu) * rs * g4.x + b4.x;
    o.y = (v.y - mu) * rs * g4.y + b4.y;
    o.z = (v.z - mu) * rs * g4.z + b4.z;
    o.w = (v.w - mu) * rs * g4.w + b4.w;
    *(float4*)(out + row * D_DIM + l * 4) = o;
}

extern "C" void kernel_launch(void* const* d_in, const int* in_sizes, int n_in,
                              void* d_out, int out_size, void* d_ws, size_t ws_size,
                              hipStream_t stream) {
    const float* parent = (const float*)d_in[0];
    const float* child  = (const float*)d_in[1];
    const int*   cidx   = (const int*)d_in[2];
    const float* Wq     = (const float*)d_in[3];
    const float* Wkv    = (const float*)d_in[4];
    const float* pos    = (const float*)d_in[5];
    const float* Wout   = (const float*)d_in[6];
    const float* bout   = (const float*)d_in[7];
    const float* gamma  = (const float*)d_in[8];
    const float* beta   = (const float*)d_in[9];
    const int N = in_sizes[0] / D_DIM;  // 16384

    char* ws = (char*)d_ws;
    float*  x_ws = (float*)ws;                                  // N*256 fp32 = 16 MB
    ushort* Am   = (ushort*)(ws + (size_t)N * D_DIM * 4);       // N*1024 bf16 = 32 MB (A2, then m2)
    ushort* Bc2t = (ushort*)(ws + (size_t)N * D_DIM * 4 + (size_t)N * 1024 * 2);  // 512 KB
    ushort* Cc2t = Bc2t + 1024 * 256;                           // 512 KB

    k_combine_B<<<1024, 256, 0, stream>>>(Wq, Wkv, Bc2t);
    k_combine_C<<<1024, 256, 0, stream>>>(Wkv, Wout, Cc2t);
    // A2[b, h*256+d] = parent @ Bc2t^T : M=16384, N=1024, K=256
    k_gemm<true, false><<<dim3(1024 / 64, N / 64), 256, 0, stream>>>(
        parent, Bc2t, Am, nullptr, nullptr, N, 1024, 256);
    k_attn<<<N, 256, 0, stream>>>(child, cidx, pos, Am);
    // x = m2 @ Cc2t^T + parent + bout : M=16384, N=256, K=1024
    k_gemm<false, true><<<dim3(256 / 64, N / 64), 256, 0, stream>>>(
        Am, Cc2t, x_ws, parent, bout, N, 256, 1024);
    k_ln<<<N / 4, 256, 0, stream>>>(x_ws, gamma, beta, (float*)d_out);
}

// Round 2
// 788.220 us; speedup vs baseline: 1.0492x; 1.0492x over previous
//
#include <hip/hip_runtime.h>
#include <hip/hip_bf16.h>

typedef __attribute__((ext_vector_type(8))) short short8;
typedef __attribute__((ext_vector_type(4))) float f32x4;

#define D_DIM 256
#define NC_DIM 32
#define KV_PAD 260   // 256+4 floats: breaks power-of-2 row stride for column-ish reads

__device__ __forceinline__ ushort f2bf(float x) {
    union { float f; unsigned u; } v; v.f = x;
    unsigned r = (v.u + 0x7fffu + ((v.u >> 16) & 1u)) >> 16;  // RNE
    return (ushort)r;
}
__device__ __forceinline__ float bf2f(ushort u) {
    union { unsigned u32; float f; } v; v.u32 = ((unsigned)u) << 16;
    return v.f;
}

// async global->LDS, 16B per lane. LDS dest = uniform base + lane*16 (m104 caveat:
// layout must be contiguous in lane order — no padding in staged tiles).
__device__ __forceinline__ void gload_lds16(const ushort* g, ushort* lds) {
    __builtin_amdgcn_global_load_lds(
        (const __attribute__((address_space(1))) unsigned int*)g,
        (__attribute__((address_space(3))) unsigned int*)lds, 16, 0, 0);
}

// parent fp32 -> bf16, 8 floats/thread
__global__ __launch_bounds__(256)
void k_cvt(const float4* __restrict__ src, uint4* __restrict__ dst) {
    int j = blockIdx.x * 256 + threadIdx.x;
    float4 a = src[2 * j], b = src[2 * j + 1];
    union { ushort us[8]; uint4 v; } pk;
    pk.us[0] = f2bf(a.x); pk.us[1] = f2bf(a.y); pk.us[2] = f2bf(a.z); pk.us[3] = f2bf(a.w);
    pk.us[4] = f2bf(b.x); pk.us[5] = f2bf(b.y); pk.us[6] = f2bf(b.z); pk.us[7] = f2bf(b.w);
    dst[j] = pk.v;
}

// Bc2t[(h*256+d)][i] = sum_j Wq[h*64+j, i] * Wkv[h*64+j, d]   (bf16, [1024 x 256], K-major)
__global__ __launch_bounds__(256)
void k_combine_B(const float* __restrict__ Wq, const float* __restrict__ Wkv,
                 ushort* __restrict__ Bc2t) {
    int bid = blockIdx.x;
    int h = bid >> 8, d = bid & 255;
    int i = threadIdx.x;
    __shared__ float wk_s[64];
    if (i < 64) wk_s[i] = Wkv[(size_t)(h * 64 + i) * D_DIM + d];
    __syncthreads();
    float s = 0.f;
#pragma unroll 8
    for (int j = 0; j < 64; j++)
        s = fmaf(Wq[(size_t)(h * 64 + j) * D_DIM + i], wk_s[j], s);
    Bc2t[(size_t)(h * 256 + d) * D_DIM + i] = f2bf(s);
}

// Cc2t[i][h*256+d] = sum_dk Wkv[256 + h*64+dk, d] * Wout[i, h*64+dk]  (bf16, [256 x 1024], K-major)
__global__ __launch_bounds__(256)
void k_combine_C(const float* __restrict__ Wkv, const float* __restrict__ Wout,
                 ushort* __restrict__ Cc2t) {
    int bid = blockIdx.x;
    int h = bid >> 8, i = bid & 255;
    int d = threadIdx.x;
    __shared__ float wo_s[64];
    if (d < 64) wo_s[d] = Wout[(size_t)i * D_DIM + h * 64 + d];
    __syncthreads();
    const float* Wv = Wkv + 256 * D_DIM;
    float s = 0.f;
#pragma unroll 8
    for (int dk = 0; dk < 64; dk++)
        s = fmaf(Wv[(size_t)(h * 64 + dk) * D_DIM + d], wo_s[dk], s);
    Cc2t[(size_t)i * 1024 + h * 256 + d] = f2bf(s);
}

// C[M,N] = A[M,K] @ Bt[N,K]^T, bf16 in, m97 structure: 128x128 tile, BK=64,
// global_load_lds width 16, 4 waves in 2x2, 4x4 16x16x32 MFMA acc each.
// EPI_RES: C fp32 = acc + resid + bias; else C bf16.
template <bool EPI_RES>
__global__ __launch_bounds__(256, 2)
void k_gemm(const ushort* __restrict__ A, const ushort* __restrict__ Bt,
            void* __restrict__ Cp, const float* __restrict__ resid,
            const float* __restrict__ bias, int M, int N, int K) {
    __shared__ ushort As[128][64];   // no pad: global_load_lds lane-order constraint
    __shared__ ushort Bs[128][64];
    const int tid = threadIdx.x;
    const int w = tid >> 6, l = tid & 63;
    const int m0 = blockIdx.y * 128, n0 = blockIdx.x * 128;
    const int wr = (w >> 1) * 64, wc = (w & 1) * 64;
    const int srow = l >> 3, scol = (l & 7) * 8;   // lane's slot in an 8-row/1KB chunk
    f32x4 acc[4][4] = {};

    for (int k0 = 0; k0 < K; k0 += 64) {
        __syncthreads();
#pragma unroll
        for (int j = 0; j < 4; j++) {
            int c = w * 4 + j;            // chunk 0..15, 8 rows each
            int r = c * 8 + srow;
            gload_lds16(A  + (size_t)(m0 + r) * K + k0 + scol, &As[c * 8][0]);
            gload_lds16(Bt + (size_t)(n0 + r) * K + k0 + scol, &Bs[c * 8][0]);
        }
        __syncthreads();   // compiler emits s_waitcnt vmcnt(0) before s_barrier
#pragma unroll
        for (int ks = 0; ks < 2; ks++) {
            short8 af[4], bf[4];
#pragma unroll
            for (int i = 0; i < 4; i++)
                af[i] = *(const short8*)&As[wr + i * 16 + (l & 15)][ks * 32 + (l >> 4) * 8];
#pragma unroll
            for (int i = 0; i < 4; i++)
                bf[i] = *(const short8*)&Bs[wc + i * 16 + (l & 15)][ks * 32 + (l >> 4) * 8];
#pragma unroll
            for (int i = 0; i < 4; i++)
#pragma unroll
                for (int j = 0; j < 4; j++)
                    acc[i][j] = __builtin_amdgcn_mfma_f32_16x16x32_bf16(af[i], bf[j], acc[i][j], 0, 0, 0);
        }
    }
    // C/D layout: col = l&15, row = (l>>4)*4 + reg
    const int row0 = m0 + wr + (l >> 4) * 4;
    const int col0 = n0 + wc + (l & 15);
#pragma unroll
    for (int i = 0; i < 4; i++)
#pragma unroll
        for (int j = 0; j < 4; j++) {
            int col = col0 + j * 16;
#pragma unroll
            for (int r = 0; r < 4; r++) {
                int row = row0 + i * 16 + r;
                float v = acc[i][j][r];
                if (EPI_RES) {
                    ((float*)Cp)[(size_t)row * N + col] =
                        v + resid[(size_t)row * N + col] + bias[col];
                } else {
                    ((ushort*)Cp)[(size_t)row * N + col] = f2bf(v);
                }
            }
        }
}

// Per-row fused attention. 42.2 KB LDS -> 3 blocks/CU. Child row prefetched to
// registers before barrier 1. Writes m2 (bf16) in place over the A2 row.
__global__ __launch_bounds__(256, 3)
void k_attn(const float* __restrict__ child, const int* __restrict__ idx,
            const float* __restrict__ pos_emb, ushort* __restrict__ Am) {
    __shared__ int idx_s[NC_DIM];
    __shared__ float A_s[4][KV_PAD];
    __shared__ float kv_s[NC_DIM][KV_PAD];
    __shared__ float part_s[8][NC_DIM][4];
    __shared__ float att_s[NC_DIM][4];
    const int b = blockIdx.x;
    const int t = threadIdx.x;
    const int l = t & 63;

    // prefetch child row (32 KB) into registers — overlaps idx/A loads
    const float4* ch4 = (const float4*)(child + (size_t)b * NC_DIM * D_DIM);
    float4 cv[8];
#pragma unroll
    for (int i = 0; i < 8; i++) cv[i] = ch4[t + i * 256];

    if (t < NC_DIM) idx_s[t] = idx[(size_t)b * NC_DIM + t];
    if (t < 128) {
        uint4 raw = *(const uint4*)(Am + (size_t)b * 1024 + t * 8);
        const ushort* u = (const ushort*)&raw;
        int h = t >> 5, c = (t & 31) * 8;
#pragma unroll
        for (int j = 0; j < 8; j++) A_s[h][c + j] = bf2f(u[j]);
    }
    __syncthreads();

    // kvin = child + pos_emb[idx] -> LDS
#pragma unroll
    for (int i = 0; i < 8; i++) {
        int n = (t >> 6) + i * 4;
        float4 pv = ((const float4*)(pos_emb + (size_t)idx_s[n] * D_DIM))[l];
        float4 r;
        r.x = cv[i].x + pv.x; r.y = cv[i].y + pv.y;
        r.z = cv[i].z + pv.z; r.w = cv[i].w + pv.w;
        *(float4*)&kv_s[n][l * 4] = r;
    }
    __syncthreads();

    // scores partials: thread (n = t&31, chunk c = t>>5 of 32 d's), 4 heads per kv read
    {
        int n = t & 31, c = t >> 5;
        float s0 = 0, s1 = 0, s2 = 0, s3 = 0;
#pragma unroll
        for (int j = 0; j < 32; j += 4) {
            float4 kv = *(const float4*)&kv_s[n][c * 32 + j];
            float4 a0 = *(const float4*)&A_s[0][c * 32 + j];
            float4 a1 = *(const float4*)&A_s[1][c * 32 + j];
            float4 a2 = *(const float4*)&A_s[2][c * 32 + j];
            float4 a3 = *(const float4*)&A_s[3][c * 32 + j];
            s0 += kv.x * a0.x + kv.y * a0.y + kv.z * a0.z + kv.w * a0.w;
            s1 += kv.x * a1.x + kv.y * a1.y + kv.z * a1.z + kv.w * a1.w;
            s2 += kv.x * a2.x + kv.y * a2.y + kv.z * a2.z + kv.w * a2.w;
            s3 += kv.x * a3.x + kv.y * a3.y + kv.z * a3.z + kv.w * a3.w;
        }
        *(float4*)&part_s[c][n][0] = make_float4(s0, s1, s2, s3);
    }
    __syncthreads();

    // combine + softmax over n
    if (t < 128) {
        int n = t & 31, h = t >> 5;
        float s = 0;
#pragma unroll
        for (int c = 0; c < 8; c++) s += part_s[c][n][h];
        s *= 0.125f;  // DK^-0.5
        float mx = s;
#pragma unroll
        for (int off = 16; off; off >>= 1) mx = fmaxf(mx, __shfl_xor(mx, off, 32));
        float e = __expf(s - mx);
        float sum = e;
#pragma unroll
        for (int off = 16; off; off >>= 1) sum += __shfl_xor(sum, off, 32);
        att_s[n][h] = e / sum;
    }
    __syncthreads();

    // m[h][d] = sum_n att[n][h]*kv[n][d]; thread = (h = t>>6, d4 = t&63).
    // att_s read is wave-uniform (LDS broadcast, free); kv read is contiguous 1KB/wave.
    {
        int h = t >> 6;
        float4 m = {0.f, 0.f, 0.f, 0.f};
#pragma unroll
        for (int n = 0; n < NC_DIM; n++) {
            float wgt = att_s[n][h];
            float4 kv = *(const float4*)&kv_s[n][l * 4];
            m.x += wgt * kv.x; m.y += wgt * kv.y;
            m.z += wgt * kv.z; m.w += wgt * kv.w;
        }
        union { ushort us[4]; uint2 v; } pk;
        pk.us[0] = f2bf(m.x); pk.us[1] = f2bf(m.y);
        pk.us[2] = f2bf(m.z); pk.us[3] = f2bf(m.w);
        *(uint2*)(Am + (size_t)b * 1024 + h * 256 + l * 4) = pk.v;
    }
}

// Row-wise LayerNorm: 4 rows/block (one wave each)
__global__ __launch_bounds__(256)
void k_ln(const float* __restrict__ x, const float* __restrict__ gamma,
          const float* __restrict__ beta, float* __restrict__ out) {
    const int t = threadIdx.x;
    const int w = t >> 6, l = t & 63;
    const size_t row = (size_t)blockIdx.x * 4 + w;
    float4 v = *(const float4*)(x + row * D_DIM + l * 4);
    float s = v.x + v.y + v.z + v.w;
    float q = v.x * v.x + v.y * v.y + v.z * v.z + v.w * v.w;
#pragma unroll
    for (int off = 32; off; off >>= 1) {
        s += __shfl_xor(s, off, 64);
        q += __shfl_xor(q, off, 64);
    }
    float mu = s * (1.f / 256.f);
    float var = q * (1.f / 256.f) - mu * mu;
    float rs = rsqrtf(var + 1e-5f);
    float4 g4 = *(const float4*)(gamma + l * 4);
    float4 b4 = *(const float4*)(beta + l * 4);
    float4 o;
    o.x = (v.x - mu) * rs * g4.x + b4.x;
    o.y = (v.y - mu) * rs * g4.y + b4.y;
    o.z = (v.z - mu) * rs * g4.z + b4.z;
    o.w = (v.w - mu) * rs * g4.w + b4.w;
    *(float4*)(out + row * D_DIM + l * 4) = o;
}

extern "C" void kernel_launch(void* const* d_in, const int* in_sizes, int n_in,
                              void* d_out, int out_size, void* d_ws, size_t ws_size,
                              hipStream_t stream) {
    const float* parent = (const float*)d_in[0];
    const float* child  = (const float*)d_in[1];
    const int*   cidx   = (const int*)d_in[2];
    const float* Wq     = (const float*)d_in[3];
    const float* Wkv    = (const float*)d_in[4];
    const float* pos    = (const float*)d_in[5];
    const float* Wout   = (const float*)d_in[6];
    const float* bout   = (const float*)d_in[7];
    const float* gamma  = (const float*)d_in[8];
    const float* beta   = (const float*)d_in[9];
    const int N = in_sizes[0] / D_DIM;  // 16384

    char* ws = (char*)d_ws;
    size_t off = 0;
    float*  x_ws = (float*)(ws + off);  off += (size_t)N * D_DIM * 4;     // 16 MB
    ushort* Am   = (ushort*)(ws + off); off += (size_t)N * 1024 * 2;      // 32 MB (A2 then m2)
    ushort* pbf  = (ushort*)(ws + off); off += (size_t)N * D_DIM * 2;     // 8 MB parent bf16
    ushort* Bc2t = (ushort*)(ws + off); off += (size_t)1024 * 256 * 2;    // 512 KB
    ushort* Cc2t = (ushort*)(ws + off);                                    // 512 KB

    k_cvt<<<(N * D_DIM / 8 + 255) / 256, 256, 0, stream>>>(
        (const float4*)parent, (uint4*)pbf);
    k_combine_B<<<1024, 256, 0, stream>>>(Wq, Wkv, Bc2t);
    k_combine_C<<<1024, 256, 0, stream>>>(Wkv, Wout, Cc2t);
    // A2[b, h*256+d] = parent @ Bc2t^T : M=16384, N=1024, K=256
    k_gemm<false><<<dim3(1024 / 128, N / 128), 256, 0, stream>>>(
        pbf, Bc2t, Am, nullptr, nullptr, N, 1024, 256);
    k_attn<<<N, 256, 0, stream>>>(child, cidx, pos, Am);
    // x = m2 @ Cc2t^T + parent + bout : M=16384, N=256, K=1024
    k_gemm<true><<<dim3(256 / 128, N / 128), 256, 0, stream>>>(
        Am, Cc2t, x_ws, parent, bout, N, 256, 1024);
    k_ln<<<N / 4, 256, 0, stream>>>(x_ws, gamma, beta, (float*)d_out);
}